// Round 8
// baseline (403.774 us; speedup 1.0000x reference)
//
#include <hip/hip_runtime.h>
#include <math.h>

#define NIMG 8
#define CIN 8
#define Hh 136
#define Ww 200
#define HW (Hh * Ww)
#define OH 272
#define OW 400
#define NINST 512
#define NPAR 169
#define TROWS 34
#define NTILES 8
#define LROWS 19
#define SPX 512                         // strip pixels (128 prod threads x 4 px)
#define PART_BYTES ((size_t)NINST * NTILES * 3 * 4)

#define PINV(x) asm volatile("" : "+v"(x))
#define PINS(x) asm volatile("" : "+s"(x))
#define MEMFENCE asm volatile("" ::: "memory")
#define SCHEDBAR __builtin_amdgcn_sched_barrier(0)

// ---- per-tile bilinear-up + sigmoid + dice partials (identical to verified) ----
__device__ __forceinline__ void dice_tile(
    const float* __restrict__ slog, const float* __restrict__ gtn,
    int oy0, int ly0, int lycnt, int tid,
    float& aI, float& aS, float& aT)
{
    const float sy = 135.0f / 271.0f;
    const float sx = 199.0f / 399.0f;
    for (int g4 = tid; g4 < TROWS * (OW / 4); g4 += 256) {
        const int ry = g4 / 100;
        const int gx = (g4 - ry * 100) * 4;
        const int oy = oy0 + ry;
        const float ysf = (float)oy * sy;
        const int y0 = (int)ysf;
        const float wy = ysf - (float)y0;
        const int y1 = (y0 + 1 > Hh - 1) ? (Hh - 1) : (y0 + 1);
        int r0i = y0 - ly0, r1i = y1 - ly0;
        r0i = r0i < 0 ? 0 : (r0i > lycnt - 1 ? lycnt - 1 : r0i);
        r1i = r1i < 0 ? 0 : (r1i > lycnt - 1 ? lycnt - 1 : r1i);
        const float* s0 = &slog[r0i * Ww];
        const float* s1 = &slog[r1i * Ww];

        const float4 t4 = *reinterpret_cast<const float4*>(gtn + ry * OW + gx);
        const float tv[4] = { t4.x, t4.y, t4.z, t4.w };
#pragma unroll
        for (int p = 0; p < 4; p++) {
            const int ox = gx + p;
            const float xsf = (float)ox * sx;
            const int x0 = (int)xsf;
            const float wx = xsf - (float)x0;
            const int x1 = (x0 + 1 > Ww - 1) ? (Ww - 1) : (x0 + 1);
            const float v00 = s0[x0];
            const float v01 = s0[x1];
            const float v10 = s1[x0];
            const float v11 = s1[x1];
            const float top = v00 + wx * (v01 - v00);
            const float bot = v10 + wx * (v11 - v10);
            const float v   = top + wy * (bot - top);
            const float s   = __fdividef(1.0f, 1.0f + __expf(-v));
            aI += s * tv[p];
            aS += s * s;
            aT += tv[p];
        }
    }
}

// ================= producer/consumer fused kernel =================
// R6 post-mortem: R4/R5/R6 (occ 31/49/57%) all ~172-186us -> not occupancy-
// bound; the shared cost is ~145 s_loads + lgkmcnt(0) drains PER 2-px
// iteration (weight reloads forced by the phase MEMFENCE). Fix: role-split.
//   waves 0-1 (producer): Wf in SGPRs (direct s_load-able), affine in VGPRs
//     (computed values — PINS on them is an illegal VGPR->SGPR copy, R7 bug),
//     layer0 for 4px/thread -> double-buffered LDS h-strip.
//   waves 2-3 (consumer): w1 (VGPR) + w2/b1/b2 resident, layers 1-2
//     from h-strip -> slog.
// Weights load ONCE per tile; 1 barrier/strip. Both role branches execute
// exactly nstrips+1 barriers (wave-uniform split at tid<128).
// FP expression trees byte-identical to verified R0-R6; h crosses in f32
// LDS exactly as R2/R4/R5 (absmax 0.0).
__global__ __launch_bounds__(256, 3) void dmh_tile(
    const float* __restrict__ feats,
    const float* __restrict__ pars,
    const float* __restrict__ iloc,
    const float* __restrict__ gt,
    const int* __restrict__ iminds,
    const int* __restrict__ lvls,
    float* __restrict__ part)
{
    __shared__ float slog[LROWS * Ww];        // 15.2 KB
    __shared__ float hbuf[2][8][SPX];         // 32 KB double-buffered h strips
    __shared__ float sred[12];

    const int n    = blockIdx.y;
    const int tile = blockIdx.x;
    const int tid  = threadIdx.x;

    const float sy = 135.0f / 271.0f;
    const int oy0 = tile * TROWS;
    const int ly0 = (int)((float)oy0 * sy);
    int lyL = (int)((float)(oy0 + TROWS - 1) * sy) + 1;
    if (lyL > Hh - 1) lyL = Hh - 1;
    const int lycnt = lyL - ly0 + 1;
    const int tpx = lycnt * Ww;
    const int nstrips = (tpx + SPX - 1) / SPX;

    const float* pp = pars + n * NPAR;

    if (tid < 128) {
        // -------- producer: layer0 --------
        const float ix = iloc[2 * n + 0];
        const float iy = iloc[2 * n + 1];
        const int   im = iminds[n];
        const float invsoi = 1.0f / (float)(64 << lvls[n]);
        float Wf[64], A0[8], Ax[8], Ay[8];
#pragma unroll
        for (int o = 0; o < 8; o++) {
            const float wx0 = pp[o * 10 + 0];
            const float wy0 = pp[o * 10 + 1];
            Ax[o] = -8.0f * invsoi * wx0;
            Ay[o] = -8.0f * invsoi * wy0;
            A0[o] = pp[152 + o] + (wx0 * (ix - 4.0f) + wy0 * (iy - 4.0f)) * invsoi;
#pragma unroll
            for (int c = 0; c < 8; c++) Wf[o * 8 + c] = pp[o * 10 + 2 + c];
        }
#pragma unroll
        for (int i = 0; i < 64; i++) PINS(Wf[i]);      // direct s_loads: legal
#pragma unroll
        for (int o = 0; o < 8; o++) { PINV(A0[o]); PINV(Ax[o]); PINV(Ay[o]); }

        const float* fbase = feats + (size_t)im * (CIN * HW) + ly0 * Ww;

        for (int k = 0; k < nstrips + 1; ++k) {
            if (k < nstrips) {
                const int base = k * SPX + tid * 4;
                if (base < tpx) {
                    const int yy = base / 200;
                    const int x  = base - yy * 200;
                    const float yf = (float)(ly0 + yy);
                    const float* fb = fbase + base;
                    float f[8][4];
#pragma unroll
                    for (int c = 0; c < 8; c++) {
                        const float4 t = *reinterpret_cast<const float4*>(fb + c * HW);
                        f[c][0] = t.x; f[c][1] = t.y; f[c][2] = t.z; f[c][3] = t.w;
                    }
#pragma unroll
                    for (int o = 0; o < 8; o++) {
                        const float pre = A0[o] + Ay[o] * yf;
                        float hv[4];
#pragma unroll
                        for (int p = 0; p < 4; p++) {
                            const float xf = (float)(x + p);
                            float a = pre + Ax[o] * xf;
#pragma unroll
                            for (int c = 0; c < 8; c++) a += Wf[o * 8 + c] * f[c][p];
                            hv[p] = fmaxf(a, 0.0f);
                        }
                        *reinterpret_cast<float4*>(&hbuf[k & 1][o][tid * 4]) =
                            make_float4(hv[0], hv[1], hv[2], hv[3]);
                    }
                }
            }
            __syncthreads();
        }
    } else {
        // -------- consumer: layers 1-2 --------
        float w1[64], w2[8], b1[8], b2;
#pragma unroll
        for (int k = 0; k < 64; k++) w1[k] = pp[80 + k];
#pragma unroll
        for (int k = 0; k < 8; k++) { w2[k] = pp[144 + k]; b1[k] = pp[160 + k]; }
        b2 = pp[168];
#pragma unroll
        for (int k = 0; k < 64; k++) PINV(w1[k]);
#pragma unroll
        for (int k = 0; k < 8; k++) { PINV(w2[k]); PINV(b1[k]); }
        PINV(b2);

        const int ct = tid - 128;

        for (int k = 0; k < nstrips + 1; ++k) {
            if (k >= 1) {
                const int km = k - 1;
                const int base = km * SPX + ct * 4;
                if (base < tpx) {
                    float o4[4];
#pragma unroll
                    for (int half = 0; half < 2; half++) {
                        float h[8][2];
#pragma unroll
                        for (int c = 0; c < 8; c++) {
                            const float2 t = *reinterpret_cast<const float2*>(
                                &hbuf[km & 1][c][ct * 4 + half * 2]);
                            h[c][0] = t.x; h[c][1] = t.y;
                        }
#pragma unroll
                        for (int p = 0; p < 2; p++) {
                            float g[8];
#pragma unroll
                            for (int o = 0; o < 8; o++) {
                                float a = b1[o];
#pragma unroll
                                for (int c = 0; c < 8; c++) a += w1[o * 8 + c] * h[c][p];
                                g[o] = fmaxf(a, 0.0f);
                            }
                            float lg = b2;
#pragma unroll
                            for (int c = 0; c < 8; c++) lg += w2[c] * g[c];
                            o4[half * 2 + p] = lg;
                        }
                    }
                    *reinterpret_cast<float4*>(&slog[base]) =
                        make_float4(o4[0], o4[1], o4[2], o4[3]);
                }
            }
            __syncthreads();
        }
    }
    // last barrier of both loops: slog complete and visible

    float aI = 0.0f, aS = 0.0f, aT = 0.0f;
    const float* gtn = gt + (size_t)n * (OH * OW) + (size_t)oy0 * OW;
    dice_tile(slog, gtn, oy0, ly0, lycnt, tid, aI, aS, aT);

#pragma unroll
    for (int off = 32; off > 0; off >>= 1) {
        aI += __shfl_down(aI, off, 64);
        aS += __shfl_down(aS, off, 64);
        aT += __shfl_down(aT, off, 64);
    }
    const int wv = tid >> 6;
    if ((tid & 63) == 0) {
        sred[wv * 3 + 0] = aI;
        sred[wv * 3 + 1] = aS;
        sred[wv * 3 + 2] = aT;
    }
    __syncthreads();
    if (tid == 0) {
        float* pt = part + (size_t)(n * NTILES + tile) * 3;
        pt[0] = sred[0] + sred[3] + sred[6] + sred[9];
        pt[1] = sred[1] + sred[4] + sred[7] + sred[10];
        pt[2] = sred[2] + sred[5] + sred[8] + sred[11];
    }
}

__global__ __launch_bounds__(256) void dmh_fin2(const float* __restrict__ part,
                                                float* __restrict__ out)
{
    const int i = blockIdx.x * 256 + threadIdx.x;
    if (i < NINST) {
        float I = 0.0f, S = 0.0f, T = 0.0f;
#pragma unroll
        for (int t = 0; t < NTILES; t++) {
            const float* pt = part + (size_t)(i * NTILES + t) * 3;
            I += pt[0]; S += pt[1]; T += pt[2];
        }
        out[i] = 1.0f - 2.0f * I / (S + T + 1e-5f);
    }
}

// ---- workspace-free fallback (R6's verified register-phase version) ----
__device__ __forceinline__ void mlp_tile_reg(
    float* __restrict__ slog, const float* __restrict__ fb0,
    const float* __restrict__ pp, int ly0, int lycnt, int tid,
    const float (&A0)[8], const float (&Ax)[8], const float (&Ay)[8])
{
    const int tpx = lycnt * Ww;
    const float* fbase = fb0 + ly0 * Ww;

    for (int px = tid * 2; px < tpx; px += 512) {
        MEMFENCE;
        float Wf[64];
#pragma unroll
        for (int o = 0; o < 8; o++)
#pragma unroll
            for (int c = 0; c < 8; c++) Wf[o * 8 + c] = pp[o * 10 + 2 + c];
#pragma unroll
        for (int i = 0; i < 64; i++) PINS(Wf[i]);

        const int yy = px / 200;
        const int x  = px - yy * 200;
        const float yf = (float)(ly0 + yy);
        const float* fb = fbase + px;
        float f[8][2];
#pragma unroll
        for (int c = 0; c < 8; c++) {
            const float2 t = *reinterpret_cast<const float2*>(fb + c * HW);
            f[c][0] = t.x; f[c][1] = t.y;
        }
        float h[8][2];
#pragma unroll
        for (int o = 0; o < 8; o++) {
            const float pre = A0[o] + Ay[o] * yf;
#pragma unroll
            for (int p = 0; p < 2; p++) {
                const float xf = (float)(x + p);
                float a = pre + Ax[o] * xf;
#pragma unroll
                for (int c = 0; c < 8; c++) a += Wf[o * 8 + c] * f[c][p];
                h[o][p] = fmaxf(a, 0.0f);
            }
        }
#pragma unroll
        for (int o = 0; o < 8; o++) { PINV(h[o][0]); PINV(h[o][1]); }
        SCHEDBAR;

        MEMFENCE;
        float w1[64];
#pragma unroll
        for (int k = 0; k < 64; k++) w1[k] = pp[80 + k];
#pragma unroll
        for (int k = 0; k < 64; k++) PINS(w1[k]);
        float w2[8], b1[8], b2;
#pragma unroll
        for (int k = 0; k < 8; k++) { w2[k] = pp[144 + k]; b1[k] = pp[160 + k]; }
        b2 = pp[168];
#pragma unroll
        for (int k = 0; k < 8; k++) { PINV(w2[k]); PINV(b1[k]); }
        PINV(b2);

        float o2[2];
#pragma unroll
        for (int p = 0; p < 2; p++) {
            float g[8];
#pragma unroll
            for (int o = 0; o < 8; o++) {
                float a = b1[o];
#pragma unroll
                for (int c = 0; c < 8; c++) a += w1[o * 8 + c] * h[c][p];
                g[o] = fmaxf(a, 0.0f);
            }
            float lg = b2;
#pragma unroll
            for (int c = 0; c < 8; c++) lg += w2[c] * g[c];
            o2[p] = lg;
        }
        *reinterpret_cast<float2*>(&slog[px]) = make_float2(o2[0], o2[1]);
        SCHEDBAR;
    }
}

__global__ __launch_bounds__(256, 3) void dmh_one(
    const float* __restrict__ feats,
    const float* __restrict__ pars,
    const float* __restrict__ iloc,
    const float* __restrict__ gt,
    const int* __restrict__ iminds,
    const int* __restrict__ lvls,
    float* __restrict__ out)
{
    __shared__ float slog[LROWS * Ww];
    __shared__ float sred[12];

    const int n   = blockIdx.x;
    const int tid = threadIdx.x;

    const float ix = iloc[2 * n + 0];
    const float iy = iloc[2 * n + 1];
    const int   im = iminds[n];
    const float invsoi = 1.0f / (float)(64 << lvls[n]);
    const float* pp = pars + n * NPAR;
    float A0[8], Ax[8], Ay[8];
#pragma unroll
    for (int o = 0; o < 8; o++) {
        const float wx0 = pp[o * 10 + 0];
        const float wy0 = pp[o * 10 + 1];
        Ax[o] = -8.0f * invsoi * wx0;
        Ay[o] = -8.0f * invsoi * wy0;
        A0[o] = pp[152 + o] + (wx0 * (ix - 4.0f) + wy0 * (iy - 4.0f)) * invsoi;
    }
#pragma unroll
    for (int o = 0; o < 8; o++) { PINV(A0[o]); PINV(Ax[o]); PINV(Ay[o]); }

    const float sy = 135.0f / 271.0f;
    const float* fb0 = feats + (size_t)im * (CIN * HW);

    float aI = 0.0f, aS = 0.0f, aT = 0.0f;
    for (int tile = 0; tile < NTILES; tile++) {
        const int oy0 = tile * TROWS;
        const int ly0 = (int)((float)oy0 * sy);
        int lyL = (int)((float)(oy0 + TROWS - 1) * sy) + 1;
        if (lyL > Hh - 1) lyL = Hh - 1;
        const int lycnt = lyL - ly0 + 1;

        mlp_tile_reg(slog, fb0, pp, ly0, lycnt, tid, A0, Ax, Ay);
        __syncthreads();
        const float* gtn = gt + (size_t)n * (OH * OW) + (size_t)oy0 * OW;
        dice_tile(slog, gtn, oy0, ly0, lycnt, tid, aI, aS, aT);
        __syncthreads();
    }

#pragma unroll
    for (int off = 32; off > 0; off >>= 1) {
        aI += __shfl_down(aI, off, 64);
        aS += __shfl_down(aS, off, 64);
        aT += __shfl_down(aT, off, 64);
    }
    const int wv = tid >> 6;
    if ((tid & 63) == 0) {
        sred[wv * 3 + 0] = aI;
        sred[wv * 3 + 1] = aS;
        sred[wv * 3 + 2] = aT;
    }
    __syncthreads();
    if (tid == 0) {
        const float I = sred[0] + sred[3] + sred[6] + sred[9];
        const float S = sred[1] + sred[4] + sred[7] + sred[10];
        const float T = sred[2] + sred[5] + sred[8] + sred[11];
        out[n] = 1.0f - 2.0f * I / (S + T + 1e-5f);
    }
}

extern "C" void kernel_launch(void* const* d_in, const int* in_sizes, int n_in,
                              void* d_out, int out_size, void* d_ws, size_t ws_size,
                              hipStream_t stream) {
    const float* feats  = (const float*)d_in[0];
    const float* pars   = (const float*)d_in[1];
    const float* iloc   = (const float*)d_in[2];
    const float* gt     = (const float*)d_in[3];
    const int*   iminds = (const int*)d_in[4];
    const int*   lvls   = (const int*)d_in[5];

    if (ws_size >= PART_BYTES) {
        float* part = (float*)d_ws;
        dim3 g(NTILES, NINST);
        dmh_tile<<<g, 256, 0, stream>>>(feats, pars, iloc, gt, iminds, lvls, part);
        dmh_fin2<<<(NINST + 255) / 256, 256, 0, stream>>>(part, (float*)d_out);
    } else {
        dmh_one<<<NINST, 256, 0, stream>>>(feats, pars, iloc, gt, iminds, lvls,
                                           (float*)d_out);
    }
}

// Round 9
// 383.226 us; speedup vs baseline: 1.0536x; 1.0536x over previous
//
#include <hip/hip_runtime.h>
#include <math.h>

#define NIMG 8
#define CIN 8
#define Hh 136
#define Ww 200
#define HW (Hh * Ww)
#define OH 272
#define OW 400
#define NINST 512
#define NPAR 169
#define TROWS 34
#define NTILES 8
#define LROWS 19
#define SPX 512                         // strip pixels (2 px per thread)
#define PART_BYTES ((size_t)NINST * NTILES * 3 * 4)

#define PINV(x) asm volatile("" : "+v"(x))
#define PINS(x) asm volatile("" : "+s"(x))
#define MEMFENCE asm volatile("" ::: "memory")

// ---- two-pass MLP over 512-px strips, with cross-strip feature prefetch ----
// R8 post-mortem: all four structures (occ 31-57%) land 172-191us -> ~55% of
// cycles are unhidden LOAD stalls (feature loads pinned per-iteration by the
// phase MEMFENCE; dice gt loads consumed immediately). Fix (T14): issue strip
// s+1's feature loads during strip s's pass A — they stay in flight across
// hbuf-write + barrier + w1 s_loads + pass B (>1000 cyc of cover); the
// register copy at pass-B end is the only wait point.
// FP expression trees byte-identical to verified R5 (absmax 0.0).
__device__ __forceinline__ void mlp_tile_pf(
    float* __restrict__ slog, float* __restrict__ hbuf,
    const float* __restrict__ fb0, const float* __restrict__ pp,
    int ly0, int lycnt, int tid,
    const float (&A0)[8], const float (&Ax)[8], const float (&Ay)[8])
{
    const int tpx = lycnt * Ww;                 // tile pixels (<= 3800)
    const float* fbase = fb0 + ly0 * Ww;        // contiguous region per plane

    // preload strip 0 features
    float fc[8][2];
    {
        const int px = tid * 2;
        if (px < tpx) {
#pragma unroll
            for (int c = 0; c < 8; c++) {
                const float2 t = *reinterpret_cast<const float2*>(fbase + px + c * HW);
                fc[c][0] = t.x; fc[c][1] = t.y;
            }
        }
    }

    for (int p0 = 0; p0 < tpx; p0 += SPX) {
        const int px  = p0 + tid * 2;
        const bool act = px < tpx;

        // ---------- pass A: layer0 + relu -> hbuf (features from fc) ----------
        MEMFENCE;                                // keep Wf pass-local
        float Wf[64];
#pragma unroll
        for (int o = 0; o < 8; o++)
#pragma unroll
            for (int c = 0; c < 8; c++) Wf[o * 8 + c] = pp[o * 10 + 2 + c];
#pragma unroll
        for (int i = 0; i < 64; i++) PINS(Wf[i]);

        if (act) {
            const int yy = px / 200;
            const int x  = px - yy * 200;
            const float yf = (float)(ly0 + yy);
#pragma unroll
            for (int o = 0; o < 8; o++) {
                const float pre = A0[o] + Ay[o] * yf;
                float hv[2];
#pragma unroll
                for (int p = 0; p < 2; p++) {
                    const float xf = (float)(x + p);
                    float a = pre + Ax[o] * xf;
#pragma unroll
                    for (int c = 0; c < 8; c++) a += Wf[o * 8 + c] * fc[c][p];
                    hv[p] = fmaxf(a, 0.0f);
                }
                *reinterpret_cast<float2*>(&hbuf[o * SPX + tid * 2]) =
                    make_float2(hv[0], hv[1]);
            }
        }

        // prefetch next strip's features — in flight across sync + pass B
        const int pxn = px + SPX;
        float fn[8][2];
#pragma unroll
        for (int c = 0; c < 8; c++) { fn[c][0] = 0.0f; fn[c][1] = 0.0f; }
        if (pxn < tpx) {
#pragma unroll
            for (int c = 0; c < 8; c++) {
                const float2 t = *reinterpret_cast<const float2*>(fbase + pxn + c * HW);
                fn[c][0] = t.x; fn[c][1] = t.y;
            }
        }
        __syncthreads();

        // ---------- pass B: layer1 + relu + layer2 -> slog ----------
        MEMFENCE;                                // keep w1 pass-local
        float w1[64];
#pragma unroll
        for (int k = 0; k < 64; k++) w1[k] = pp[80 + k];
#pragma unroll
        for (int k = 0; k < 64; k++) PINS(w1[k]);
        float w2[8], b1[8], b2;
#pragma unroll
        for (int k = 0; k < 8; k++) { w2[k] = pp[144 + k]; b1[k] = pp[160 + k]; }
        b2 = pp[168];
#pragma unroll
        for (int k = 0; k < 8; k++) { PINV(w2[k]); PINV(b1[k]); }
        PINV(b2);

        if (act) {
            float h[8][2];
#pragma unroll
            for (int c = 0; c < 8; c++) {
                const float2 t = *reinterpret_cast<const float2*>(
                    &hbuf[c * SPX + tid * 2]);
                h[c][0] = t.x; h[c][1] = t.y;
            }
            float o2[2];
#pragma unroll
            for (int p = 0; p < 2; p++) {
                float g[8];
#pragma unroll
                for (int o = 0; o < 8; o++) {
                    float a = b1[o];
#pragma unroll
                    for (int c = 0; c < 8; c++) a += w1[o * 8 + c] * h[c][p];
                    g[o] = fmaxf(a, 0.0f);
                }
                float lg = b2;
#pragma unroll
                for (int c = 0; c < 8; c++) lg += w2[c] * g[c];
                o2[p] = lg;
            }
            *reinterpret_cast<float2*>(&slog[px]) = make_float2(o2[0], o2[1]);
        }
        // rotate prefetch buffer (forces the vmcnt wait here, ~1000+ cyc after issue)
#pragma unroll
        for (int c = 0; c < 8; c++) { fc[c][0] = fn[c][0]; fc[c][1] = fn[c][1]; }
        __syncthreads();                         // hbuf reused next strip
    }
}

// ---- per-tile bilinear-up + sigmoid + dice partials, gt prefetched 1 ahead ----
// Math and accumulation order identical to the verified R0-R8 dice_tile.
__device__ __forceinline__ void dice_tile(
    const float* __restrict__ slog, const float* __restrict__ gtn,
    int oy0, int ly0, int lycnt, int tid,
    float& aI, float& aS, float& aT)
{
    const float sy = 135.0f / 271.0f;
    const float sx = 199.0f / 399.0f;
    const int NG = TROWS * (OW / 4);

    int g4 = tid;
    int ry = g4 / 100;
    int gx = (g4 - ry * 100) * 4;
    float4 t4 = make_float4(0.0f, 0.0f, 0.0f, 0.0f);
    if (g4 < NG) t4 = *reinterpret_cast<const float4*>(gtn + ry * OW + gx);

    for (; g4 < NG; g4 += 256) {
        // prefetch next iteration's gt quad
        const int g4n = g4 + 256;
        const int ryn = g4n / 100;
        const int gxn = (g4n - ryn * 100) * 4;
        float4 t4n = make_float4(0.0f, 0.0f, 0.0f, 0.0f);
        if (g4n < NG) t4n = *reinterpret_cast<const float4*>(gtn + ryn * OW + gxn);

        // process current
        const int oy = oy0 + ry;
        const float ysf = (float)oy * sy;
        const int y0 = (int)ysf;
        const float wy = ysf - (float)y0;
        const int y1 = (y0 + 1 > Hh - 1) ? (Hh - 1) : (y0 + 1);
        int r0i = y0 - ly0, r1i = y1 - ly0;
        r0i = r0i < 0 ? 0 : (r0i > lycnt - 1 ? lycnt - 1 : r0i);
        r1i = r1i < 0 ? 0 : (r1i > lycnt - 1 ? lycnt - 1 : r1i);
        const float* s0 = &slog[r0i * Ww];
        const float* s1 = &slog[r1i * Ww];

        const float tv[4] = { t4.x, t4.y, t4.z, t4.w };
#pragma unroll
        for (int p = 0; p < 4; p++) {
            const int ox = gx + p;
            const float xsf = (float)ox * sx;
            const int x0 = (int)xsf;
            const float wx = xsf - (float)x0;
            const int x1 = (x0 + 1 > Ww - 1) ? (Ww - 1) : (x0 + 1);
            const float v00 = s0[x0];
            const float v01 = s0[x1];
            const float v10 = s1[x0];
            const float v11 = s1[x1];
            const float top = v00 + wx * (v01 - v00);
            const float bot = v10 + wx * (v11 - v10);
            const float v   = top + wy * (bot - top);
            const float s   = __fdividef(1.0f, 1.0f + __expf(-v));
            aI += s * tv[p];
            aS += s * s;
            aT += tv[p];
        }

        t4 = t4n; ry = ryn; gx = gxn;
    }
}

// Affine precompute only (24 resident VGPRs) — matrices stay pass-local.
#define LOAD_AFFINE                                                             \
    const float ix = iloc[2 * n + 0];                                           \
    const float iy = iloc[2 * n + 1];                                           \
    const int   im = iminds[n];                                                 \
    const float invsoi = 1.0f / (float)(64 << lvls[n]);                         \
    const float* pp = pars + n * NPAR;                                          \
    float A0[8], Ax[8], Ay[8];                                                  \
    _Pragma("unroll")                                                           \
    for (int o = 0; o < 8; o++) {                                               \
        const float wx0 = pp[o * 10 + 0];                                       \
        const float wy0 = pp[o * 10 + 1];                                       \
        Ax[o] = -8.0f * invsoi * wx0;                                           \
        Ay[o] = -8.0f * invsoi * wy0;                                           \
        A0[o] = pp[152 + o] + (wx0 * (ix - 4.0f) + wy0 * (iy - 4.0f)) * invsoi; \
    }                                                                           \
    _Pragma("unroll")                                                           \
    for (int o = 0; o < 8; o++) { PINV(A0[o]); PINV(Ax[o]); PINV(Ay[o]); }

// ---------------- Fused: MLP -> LDS logits -> dice partials ----------------
__global__ __launch_bounds__(256, 5) void dmh_tile(
    const float* __restrict__ feats,
    const float* __restrict__ pars,
    const float* __restrict__ iloc,
    const float* __restrict__ gt,
    const int* __restrict__ iminds,
    const int* __restrict__ lvls,
    float* __restrict__ part)
{
    __shared__ float slog[LROWS * Ww];
    __shared__ float hbuf[8 * SPX];
    __shared__ float sred[12];

    const int n    = blockIdx.y;
    const int tile = blockIdx.x;
    const int tid  = threadIdx.x;

    LOAD_AFFINE

    const float sy = 135.0f / 271.0f;
    const int oy0 = tile * TROWS;
    const int ly0 = (int)((float)oy0 * sy);
    int lyL = (int)((float)(oy0 + TROWS - 1) * sy) + 1;
    if (lyL > Hh - 1) lyL = Hh - 1;
    const int lycnt = lyL - ly0 + 1;

    const float* fb0 = feats + (size_t)im * (CIN * HW);
    mlp_tile_pf(slog, hbuf, fb0, pp, ly0, lycnt, tid, A0, Ax, Ay);
    // trailing __syncthreads in the strip loop: slog is ready

    float aI = 0.0f, aS = 0.0f, aT = 0.0f;
    const float* gtn = gt + (size_t)n * (OH * OW) + (size_t)oy0 * OW;
    dice_tile(slog, gtn, oy0, ly0, lycnt, tid, aI, aS, aT);

#pragma unroll
    for (int off = 32; off > 0; off >>= 1) {
        aI += __shfl_down(aI, off, 64);
        aS += __shfl_down(aS, off, 64);
        aT += __shfl_down(aT, off, 64);
    }
    const int wv = tid >> 6;
    if ((tid & 63) == 0) {
        sred[wv * 3 + 0] = aI;
        sred[wv * 3 + 1] = aS;
        sred[wv * 3 + 2] = aT;
    }
    __syncthreads();
    if (tid == 0) {
        float* pt = part + (size_t)(n * NTILES + tile) * 3;
        pt[0] = sred[0] + sred[3] + sred[6] + sred[9];
        pt[1] = sred[1] + sred[4] + sred[7] + sred[10];
        pt[2] = sred[2] + sred[5] + sred[8] + sred[11];
    }
}

__global__ __launch_bounds__(256) void dmh_fin2(const float* __restrict__ part,
                                                float* __restrict__ out)
{
    const int i = blockIdx.x * 256 + threadIdx.x;
    if (i < NINST) {
        float I = 0.0f, S = 0.0f, T = 0.0f;
#pragma unroll
        for (int t = 0; t < NTILES; t++) {
            const float* pt = part + (size_t)(i * NTILES + t) * 3;
            I += pt[0]; S += pt[1]; T += pt[2];
        }
        out[i] = 1.0f - 2.0f * I / (S + T + 1e-5f);
    }
}

// ---- workspace-free fallback: one block per instance, loops over tiles ----
__global__ __launch_bounds__(256, 5) void dmh_one(
    const float* __restrict__ feats,
    const float* __restrict__ pars,
    const float* __restrict__ iloc,
    const float* __restrict__ gt,
    const int* __restrict__ iminds,
    const int* __restrict__ lvls,
    float* __restrict__ out)
{
    __shared__ float slog[LROWS * Ww];
    __shared__ float hbuf[8 * SPX];
    __shared__ float sred[12];

    const int n   = blockIdx.x;
    const int tid = threadIdx.x;

    LOAD_AFFINE

    const float sy = 135.0f / 271.0f;
    const float* fb0 = feats + (size_t)im * (CIN * HW);

    float aI = 0.0f, aS = 0.0f, aT = 0.0f;
    for (int tile = 0; tile < NTILES; tile++) {
        const int oy0 = tile * TROWS;
        const int ly0 = (int)((float)oy0 * sy);
        int lyL = (int)((float)(oy0 + TROWS - 1) * sy) + 1;
        if (lyL > Hh - 1) lyL = Hh - 1;
        const int lycnt = lyL - ly0 + 1;

        mlp_tile_pf(slog, hbuf, fb0, pp, ly0, lycnt, tid, A0, Ax, Ay);
        const float* gtn = gt + (size_t)n * (OH * OW) + (size_t)oy0 * OW;
        dice_tile(slog, gtn, oy0, ly0, lycnt, tid, aI, aS, aT);
        __syncthreads();  // slog reused next tile
    }

#pragma unroll
    for (int off = 32; off > 0; off >>= 1) {
        aI += __shfl_down(aI, off, 64);
        aS += __shfl_down(aS, off, 64);
        aT += __shfl_down(aT, off, 64);
    }
    const int wv = tid >> 6;
    if ((tid & 63) == 0) {
        sred[wv * 3 + 0] = aI;
        sred[wv * 3 + 1] = aS;
        sred[wv * 3 + 2] = aT;
    }
    __syncthreads();
    if (tid == 0) {
        const float I = sred[0] + sred[3] + sred[6] + sred[9];
        const float S = sred[1] + sred[4] + sred[7] + sred[10];
        const float T = sred[2] + sred[5] + sred[8] + sred[11];
        out[n] = 1.0f - 2.0f * I / (S + T + 1e-5f);
    }
}

extern "C" void kernel_launch(void* const* d_in, const int* in_sizes, int n_in,
                              void* d_out, int out_size, void* d_ws, size_t ws_size,
                              hipStream_t stream) {
    const float* feats  = (const float*)d_in[0];
    const float* pars   = (const float*)d_in[1];
    const float* iloc   = (const float*)d_in[2];
    const float* gt     = (const float*)d_in[3];
    const int*   iminds = (const int*)d_in[4];
    const int*   lvls   = (const int*)d_in[5];

    if (ws_size >= PART_BYTES) {
        float* part = (float*)d_ws;
        dim3 g(NTILES, NINST);
        dmh_tile<<<g, 256, 0, stream>>>(feats, pars, iloc, gt, iminds, lvls, part);
        dmh_fin2<<<(NINST + 255) / 256, 256, 0, stream>>>(part, (float*)d_out);
    } else {
        dmh_one<<<NINST, 256, 0, stream>>>(feats, pars, iloc, gt, iminds, lvls,
                                           (float*)d_out);
    }
}